// Round 1
// baseline (705.907 us; speedup 1.0000x reference)
//
#include <hip/hip_runtime.h>
#include <math.h>

#define NN 50000
#define NE 800000
#define FT 128
#define NG 512
#define F1 512
#define F2 256
#define NC 32
#define BN_EPS 1e-5f

// ---------------- graph structure ----------------

__global__ __launch_bounds__(256) void k_hist(const int* __restrict__ ei, int* __restrict__ cnt) {
  int e = blockIdx.x * 256 + threadIdx.x;
  if (e < NE) atomicAdd(&cnt[ei[NE + e]], 1);
}

__global__ __launch_bounds__(256) void k_dinv(const int* __restrict__ cnt, float* __restrict__ dinv) {
  int i = blockIdx.x * 256 + threadIdx.x;
  if (i < NN) dinv[i] = rsqrtf((float)(cnt[i] + 1));  // +1 self loop
}

__global__ __launch_bounds__(256) void k_scan1(const int* __restrict__ cnt, int* __restrict__ bsum) {
  __shared__ int s[256];
  int t = threadIdx.x, i = blockIdx.x * 256 + t;
  s[t] = (i < NN) ? cnt[i] : 0;
  __syncthreads();
  for (int d = 128; d > 0; d >>= 1) {
    if (t < d) s[t] += s[t + d];
    __syncthreads();
  }
  if (t == 0) bsum[blockIdx.x] = s[0];
}

__global__ __launch_bounds__(256) void k_scan2(const int* __restrict__ bsum, int* __restrict__ bscan, int nb) {
  __shared__ int s[256];
  int t = threadIdx.x;
  int v = (t < nb) ? bsum[t] : 0;
  s[t] = v; __syncthreads();
  for (int d = 1; d < 256; d <<= 1) {
    int a = (t >= d) ? s[t - d] : 0;
    __syncthreads();
    s[t] += a;
    __syncthreads();
  }
  bscan[t] = s[t] - v;  // exclusive
}

__global__ __launch_bounds__(256) void k_scan3(const int* __restrict__ cnt, const int* __restrict__ bscan,
                                               int* __restrict__ off) {
  __shared__ int s[256];
  int t = threadIdx.x, i = blockIdx.x * 256 + t;
  int v = (i < NN) ? cnt[i] : 0;
  s[t] = v; __syncthreads();
  for (int d = 1; d < 256; d <<= 1) {
    int a = (t >= d) ? s[t - d] : 0;
    __syncthreads();
    s[t] += a;
    __syncthreads();
  }
  int base = bscan[blockIdx.x];
  if (i < NN) off[i] = base + s[t] - v;       // exclusive prefix
  if (i == NN - 1) off[NN] = base + s[t];     // total = NE
}

__global__ __launch_bounds__(256) void k_fill(const int* __restrict__ ei, const int* __restrict__ off,
                                              int* __restrict__ cur, const float* __restrict__ dinv,
                                              int* __restrict__ csrc, float* __restrict__ cw) {
  int e = blockIdx.x * 256 + threadIdx.x;
  if (e >= NE) return;
  int s = ei[e], d = ei[NE + e];
  int p = off[d] + atomicAdd(&cur[d], 1);
  csrc[p] = s;
  cw[p] = dinv[s] * dinv[d];
}

// ---------------- GCN layer: GEMM (h = x @ W) ----------------
// block = 256 thr, 16 rows/block, W fully staged in 64KB LDS.
// thread: cg = t&31 -> cols [4cg,4cg+4), rr = t>>5 -> rows {2rr, 2rr+1}

__global__ __launch_bounds__(256) void k_gemm(const float* __restrict__ X, const float* __restrict__ W,
                                              float* __restrict__ O, int nrows) {
  __shared__ float sW[FT * FT];
  int t = threadIdx.x;
#pragma unroll
  for (int i = 0; i < 16; ++i) {
    int idx = (t + i * 256) * 4;
    *(float4*)&sW[idx] = *(const float4*)&W[idx];
  }
  __syncthreads();
  int cg = t & 31;
  int rr = t >> 5;
  int r0 = blockIdx.x * 16 + rr * 2;
  if (r0 >= nrows) return;
  float acc0[4] = {0.f, 0.f, 0.f, 0.f};
  float acc1[4] = {0.f, 0.f, 0.f, 0.f};
  const float* x0 = X + (size_t)r0 * FT;
  const float* x1 = x0 + FT;
  for (int k = 0; k < FT; k += 4) {
    float4 a0 = *(const float4*)&x0[k];
    float4 a1 = *(const float4*)&x1[k];
    const float* pa0 = (const float*)&a0;
    const float* pa1 = (const float*)&a1;
#pragma unroll
    for (int kk = 0; kk < 4; ++kk) {
      float4 w = *(const float4*)&sW[(k + kk) * FT + cg * 4];
      float v0 = pa0[kk], v1 = pa1[kk];
      acc0[0] += v0 * w.x; acc0[1] += v0 * w.y; acc0[2] += v0 * w.z; acc0[3] += v0 * w.w;
      acc1[0] += v1 * w.x; acc1[1] += v1 * w.y; acc1[2] += v1 * w.z; acc1[3] += v1 * w.w;
    }
  }
  *(float4*)&O[(size_t)r0 * FT + cg * 4] = *(float4*)acc0;
  *(float4*)&O[(size_t)(r0 + 1) * FT + cg * 4] = *(float4*)acc1;
}

// ---------------- GCN layer: aggregate (wave per node) ----------------

__global__ __launch_bounds__(256) void k_agg(const float* __restrict__ H, const float* __restrict__ dinv,
                                             const int* __restrict__ off, const int* __restrict__ csrc,
                                             const float* __restrict__ cw, const float* __restrict__ bias,
                                             float* __restrict__ O) {
  int node = (blockIdx.x * 256 + threadIdx.x) >> 6;
  int lane = threadIdx.x & 63;
  if (node >= NN) return;
  float di = dinv[node];
  float2 acc = ((const float2*)(H + (size_t)node * FT))[lane];
  float sw = di * di;  // self-loop norm
  acc.x *= sw; acc.y *= sw;
  int e0 = off[node], e1 = off[node + 1];
  for (int e = e0; e < e1; ++e) {
    int s = csrc[e];
    float w = cw[e];
    float2 v = ((const float2*)(H + (size_t)s * FT))[lane];
    acc.x += v.x * w; acc.y += v.y * w;
  }
  float2 b = ((const float2*)bias)[lane];
  acc.x = fmaxf(acc.x + b.x, 0.f);
  acc.y = fmaxf(acc.y + b.y, 0.f);
  ((float2*)(O + (size_t)node * FT))[lane] = acc;
}

// ---------------- pooling ----------------

__global__ __launch_bounds__(256) void k_bounds(const int* __restrict__ batch, int* __restrict__ gstart,
                                                int* __restrict__ gend) {
  int i = blockIdx.x * 256 + threadIdx.x;
  if (i >= NN) return;
  int b = batch[i];
  if (i == 0 || batch[i - 1] != b) gstart[b] = i;
  if (i == NN - 1 || batch[i + 1] != b) gend[b] = i + 1;
}

__global__ __launch_bounds__(128) void k_pool(const float* __restrict__ X, const int* __restrict__ gstart,
                                              const int* __restrict__ gend, float* __restrict__ pool) {
  int g = blockIdx.x, t = threadIdx.x;
  float s = 0.f;
  int n0 = gstart[g], n1 = gend[g];
  for (int n = n0; n < n1; ++n) s += X[(size_t)n * FT + t];
  pool[g * FT + t] = s;
}

// ---------------- MLP head ----------------

__global__ __launch_bounds__(256) void k_fc1(const float* __restrict__ P, const float* __restrict__ W,
                                             const float* __restrict__ B, float* __restrict__ O) {
  __shared__ float sp[FT];
  int g = blockIdx.x, t = threadIdx.x;
  if (t < FT) sp[t] = P[g * FT + t];
  __syncthreads();
  float a0 = B[t], a1 = B[t + 256];
  for (int k = 0; k < FT; ++k) {
    float x = sp[k];
    a0 += x * W[k * F1 + t];
    a1 += x * W[k * F1 + t + 256];
  }
  O[g * F1 + t] = fmaxf(a0, 0.f);
  O[g * F1 + t + 256] = fmaxf(a1, 0.f);
}

__global__ __launch_bounds__(256) void k_bnstats(const float* __restrict__ h, int cols,
                                                 float* __restrict__ bm, float* __restrict__ br) {
  __shared__ float ss[256], s2[256];
  int c = blockIdx.x, t = threadIdx.x;
  float a = 0.f, b = 0.f;
  for (int r = t; r < NG; r += 256) {
    float v = h[r * cols + c];
    a += v; b += v * v;
  }
  ss[t] = a; s2[t] = b; __syncthreads();
  for (int d = 128; d > 0; d >>= 1) {
    if (t < d) { ss[t] += ss[t + d]; s2[t] += s2[t + d]; }
    __syncthreads();
  }
  if (t == 0) {
    float m = ss[0] / NG;
    float var = s2[0] / NG - m * m;
    bm[c] = m;
    br[c] = rsqrtf(var + BN_EPS);
  }
}

__global__ __launch_bounds__(256) void k_fc2(const float* __restrict__ H1, const float* __restrict__ bm,
                                             const float* __restrict__ br, const float* __restrict__ gam,
                                             const float* __restrict__ bet, const float* __restrict__ W,
                                             const float* __restrict__ B, float* __restrict__ O) {
  __shared__ float sh[F1];
  int g = blockIdx.x, t = threadIdx.x;
  for (int k = t; k < F1; k += 256) {
    float v = H1[g * F1 + k];
    sh[k] = (v - bm[k]) * br[k] * gam[k] + bet[k];
  }
  __syncthreads();
  float a = B[t];
  for (int k = 0; k < F1; ++k) a += sh[k] * W[k * F2 + t];
  O[g * F2 + t] = fmaxf(a, 0.f);
}

__global__ __launch_bounds__(256) void k_fc3(const float* __restrict__ H2, const float* __restrict__ bm,
                                             const float* __restrict__ br, const float* __restrict__ gam,
                                             const float* __restrict__ bet, const float* __restrict__ W,
                                             const float* __restrict__ B, float* __restrict__ O) {
  __shared__ float sh[F2];
  int g = blockIdx.x, t = threadIdx.x;
  if (t < F2) {
    float v = H2[g * F2 + t];
    sh[t] = (v - bm[t]) * br[t] * gam[t] + bet[t];
  }
  __syncthreads();
  if (t < NC) {
    float a = B[t];
    for (int k = 0; k < F2; ++k) a += sh[k] * W[k * NC + t];
    O[g * NC + t] = 1.f / (1.f + expf(-a));
  }
}

// ---------------- launch ----------------

extern "C" void kernel_launch(void* const* d_in, const int* in_sizes, int n_in,
                              void* d_out, int out_size, void* d_ws, size_t ws_size,
                              hipStream_t stream) {
  const float* x     = (const float*)d_in[0];
  const int*   ei    = (const int*)d_in[1];
  const int*   batch = (const int*)d_in[2];
  const float* Wc[4] = {(const float*)d_in[3], (const float*)d_in[5], (const float*)d_in[7], (const float*)d_in[9]};
  const float* Bc[4] = {(const float*)d_in[4], (const float*)d_in[6], (const float*)d_in[8], (const float*)d_in[10]};
  const float* lw1 = (const float*)d_in[11]; const float* lb1 = (const float*)d_in[12];
  const float* lw2 = (const float*)d_in[13]; const float* lb2 = (const float*)d_in[14];
  const float* lw3 = (const float*)d_in[15]; const float* lb3 = (const float*)d_in[16];
  const float* g1  = (const float*)d_in[17]; const float* be1 = (const float*)d_in[18];
  const float* g2  = (const float*)d_in[19]; const float* be2 = (const float*)d_in[20];

  char* p = (char*)d_ws;
  auto take = [&](size_t bytes) {
    char* r = p;
    p += (bytes + 255) & ~(size_t)255;
    return r;
  };
  int*   cnt    = (int*)take((size_t)NN * 4);
  float* dinv   = (float*)take((size_t)NN * 4);
  int*   off    = (int*)take((size_t)(NN + 1) * 4);
  int*   cur    = (int*)take((size_t)NN * 4);
  int*   bsum   = (int*)take(256 * 4);
  int*   bscan  = (int*)take(256 * 4);
  int*   gstart = (int*)take((size_t)NG * 4);
  int*   gend   = (int*)take((size_t)NG * 4);
  int*   csrc   = (int*)take((size_t)NE * 4);
  float* cw     = (float*)take((size_t)NE * 4);
  float* bufT   = (float*)take((size_t)NN * FT * 4);
  float* bufA   = (float*)take((size_t)NN * FT * 4);
  float* bufB   = (float*)take((size_t)NN * FT * 4);
  float* pool   = (float*)take((size_t)NG * FT * 4);
  float* h1     = (float*)take((size_t)NG * F1 * 4);
  float* h2     = (float*)take((size_t)NG * F2 * 4);
  float* bnm1   = (float*)take(F1 * 4);
  float* bnr1   = (float*)take(F1 * 4);
  float* bnm2   = (float*)take(F2 * 4);
  float* bnr2   = (float*)take(F2 * 4);

  const int NB = (NN + 255) / 256;  // 196

  hipMemsetAsync(cnt, 0, (size_t)NN * 4, stream);
  hipMemsetAsync(cur, 0, (size_t)NN * 4, stream);
  hipMemsetAsync(gstart, 0, (size_t)NG * 4, stream);
  hipMemsetAsync(gend, 0, (size_t)NG * 4, stream);

  k_hist<<<NE / 256, 256, 0, stream>>>(ei, cnt);
  k_dinv<<<NB, 256, 0, stream>>>(cnt, dinv);
  k_scan1<<<NB, 256, 0, stream>>>(cnt, bsum);
  k_scan2<<<1, 256, 0, stream>>>(bsum, bscan, NB);
  k_scan3<<<NB, 256, 0, stream>>>(cnt, bscan, off);
  k_fill<<<NE / 256, 256, 0, stream>>>(ei, off, cur, dinv, csrc, cw);

  const float* in = x;
  float* outs[4] = {bufA, bufB, bufA, bufB};
  for (int l = 0; l < 4; ++l) {
    k_gemm<<<NN / 16, 256, 0, stream>>>(in, Wc[l], bufT, NN);
    k_agg<<<(NN * 64) / 256, 256, 0, stream>>>(bufT, dinv, off, csrc, cw, Bc[l], outs[l]);
    in = outs[l];
  }

  k_bounds<<<NB, 256, 0, stream>>>(batch, gstart, gend);
  k_pool<<<NG, 128, 0, stream>>>(bufB, gstart, gend, pool);

  k_fc1<<<NG, 256, 0, stream>>>(pool, lw1, lb1, h1);
  k_bnstats<<<F1, 256, 0, stream>>>(h1, F1, bnm1, bnr1);
  k_fc2<<<NG, 256, 0, stream>>>(h1, bnm1, bnr1, g1, be1, lw2, lb2, h2);
  k_bnstats<<<F2, 256, 0, stream>>>(h2, F2, bnm2, bnr2);
  k_fc3<<<NG, 256, 0, stream>>>(h2, bnm2, bnr2, g2, be2, lw3, lb3, (float*)d_out);
}

// Round 2
// 685.317 us; speedup vs baseline: 1.0300x; 1.0300x over previous
//
#include <hip/hip_runtime.h>
#include <math.h>

#define NN 50000
#define NE 800000
#define FT 128
#define NG 512
#define F1 512
#define F2 256
#define NC 32
#define BN_EPS 1e-5f

// ---------------- graph structure ----------------

__global__ __launch_bounds__(256) void k_hist(const int* __restrict__ ei, int* __restrict__ cnt) {
  int e = blockIdx.x * 256 + threadIdx.x;
  if (e < NE) atomicAdd(&cnt[ei[NE + e]], 1);
}

__global__ __launch_bounds__(256) void k_dinv(const int* __restrict__ cnt, float* __restrict__ dinv) {
  int i = blockIdx.x * 256 + threadIdx.x;
  if (i < NN) dinv[i] = rsqrtf((float)(cnt[i] + 1));  // +1 self loop
}

__global__ __launch_bounds__(256) void k_scan1(const int* __restrict__ cnt, int* __restrict__ bsum) {
  __shared__ int s[256];
  int t = threadIdx.x, i = blockIdx.x * 256 + t;
  s[t] = (i < NN) ? cnt[i] : 0;
  __syncthreads();
  for (int d = 128; d > 0; d >>= 1) {
    if (t < d) s[t] += s[t + d];
    __syncthreads();
  }
  if (t == 0) bsum[blockIdx.x] = s[0];
}

__global__ __launch_bounds__(256) void k_scan2(const int* __restrict__ bsum, int* __restrict__ bscan, int nb) {
  __shared__ int s[256];
  int t = threadIdx.x;
  int v = (t < nb) ? bsum[t] : 0;
  s[t] = v; __syncthreads();
  for (int d = 1; d < 256; d <<= 1) {
    int a = (t >= d) ? s[t - d] : 0;
    __syncthreads();
    s[t] += a;
    __syncthreads();
  }
  bscan[t] = s[t] - v;  // exclusive
}

__global__ __launch_bounds__(256) void k_scan3(const int* __restrict__ cnt, const int* __restrict__ bscan,
                                               int* __restrict__ off) {
  __shared__ int s[256];
  int t = threadIdx.x, i = blockIdx.x * 256 + t;
  int v = (i < NN) ? cnt[i] : 0;
  s[t] = v; __syncthreads();
  for (int d = 1; d < 256; d <<= 1) {
    int a = (t >= d) ? s[t - d] : 0;
    __syncthreads();
    s[t] += a;
    __syncthreads();
  }
  int base = bscan[blockIdx.x];
  if (i < NN) off[i] = base + s[t] - v;       // exclusive prefix
  if (i == NN - 1) off[NN] = base + s[t];     // total = NE
}

__global__ __launch_bounds__(256) void k_fill(const int* __restrict__ ei, const int* __restrict__ off,
                                              int* __restrict__ cur, const float* __restrict__ dinv,
                                              int2* __restrict__ ep) {
  int e = blockIdx.x * 256 + threadIdx.x;
  if (e >= NE) return;
  int s = ei[e], d = ei[NE + e];
  int p = off[d] + atomicAdd(&cur[d], 1);
  int2 v;
  v.x = s;
  v.y = __float_as_int(dinv[s] * dinv[d]);
  ep[p] = v;
}

// ---------------- GCN layer: GEMM (h = x @ W), chunk-major output ----------------
// Output layout: Oc[8][NN][16] (chunk c holds features [16c, 16c+16)).

__global__ __launch_bounds__(256) void k_gemm(const float* __restrict__ X, const float* __restrict__ W,
                                              float* __restrict__ Oc, int nrows) {
  __shared__ float sW[FT * FT];
  int t = threadIdx.x;
#pragma unroll
  for (int i = 0; i < 16; ++i) {
    int idx = (t + i * 256) * 4;
    *(float4*)&sW[idx] = *(const float4*)&W[idx];
  }
  __syncthreads();
  int cg = t & 31;
  int rr = t >> 5;
  int r0 = blockIdx.x * 16 + rr * 2;
  if (r0 >= nrows) return;
  float acc0[4] = {0.f, 0.f, 0.f, 0.f};
  float acc1[4] = {0.f, 0.f, 0.f, 0.f};
  const float* x0 = X + (size_t)r0 * FT;
  const float* x1 = x0 + FT;
  for (int k = 0; k < FT; k += 4) {
    float4 a0 = *(const float4*)&x0[k];
    float4 a1 = *(const float4*)&x1[k];
    const float* pa0 = (const float*)&a0;
    const float* pa1 = (const float*)&a1;
#pragma unroll
    for (int kk = 0; kk < 4; ++kk) {
      float4 w = *(const float4*)&sW[(k + kk) * FT + cg * 4];
      float v0 = pa0[kk], v1 = pa1[kk];
      acc0[0] += v0 * w.x; acc0[1] += v0 * w.y; acc0[2] += v0 * w.z; acc0[3] += v0 * w.w;
      acc1[0] += v1 * w.x; acc1[1] += v1 * w.y; acc1[2] += v1 * w.z; acc1[3] += v1 * w.w;
    }
  }
  int ch = cg >> 2;            // feature chunk [0,8)
  int of = (cg & 3) * 4;       // offset within chunk
  *(float4*)&Oc[((size_t)ch * NN + r0) * 16 + of] = *(float4*)acc0;
  *(float4*)&Oc[((size_t)ch * NN + r0 + 1) * 16 + of] = *(float4*)acc1;
}

// ---------------- GCN layer: aggregate, chunk x XCD pinned ----------------
// block: chunk c = blockIdx.x & 7 (-> XCD c via round-robin dispatch),
//        64 nodes, 4 lanes/node each owning a float4 of the 16-float chunk.

__global__ __launch_bounds__(256) void k_aggc(const float* __restrict__ Hc, const float* __restrict__ dinv,
                                              const int* __restrict__ off, const int2* __restrict__ ep,
                                              const float* __restrict__ bias, float* __restrict__ O) {
  int c = blockIdx.x & 7;
  int grp = blockIdx.x >> 3;
  int t = threadIdx.x;
  int node = grp * 64 + (t >> 2);
  int l = t & 3;
  if (node >= NN) return;
  const float* Hcc = Hc + (size_t)c * NN * 16;
  float di = dinv[node];
  float sw = di * di;  // self-loop norm
  float4 acc = *(const float4*)&Hcc[(size_t)node * 16 + l * 4];
  acc.x *= sw; acc.y *= sw; acc.z *= sw; acc.w *= sw;
  int e0 = off[node], e1 = off[node + 1];
  for (int e = e0; e < e1; ++e) {
    int2 p = ep[e];
    float w = __int_as_float(p.y);
    float4 v = *(const float4*)&Hcc[(size_t)p.x * 16 + l * 4];
    acc.x += v.x * w; acc.y += v.y * w; acc.z += v.z * w; acc.w += v.w * w;
  }
  float4 b = *(const float4*)&bias[c * 16 + l * 4];
  acc.x = fmaxf(acc.x + b.x, 0.f);
  acc.y = fmaxf(acc.y + b.y, 0.f);
  acc.z = fmaxf(acc.z + b.z, 0.f);
  acc.w = fmaxf(acc.w + b.w, 0.f);
  *(float4*)&O[(size_t)node * FT + c * 16 + l * 4] = acc;
}

// ---------------- pooling ----------------

__global__ __launch_bounds__(256) void k_bounds(const int* __restrict__ batch, int* __restrict__ gstart,
                                                int* __restrict__ gend) {
  int i = blockIdx.x * 256 + threadIdx.x;
  if (i >= NN) return;
  int b = batch[i];
  if (i == 0 || batch[i - 1] != b) gstart[b] = i;
  if (i == NN - 1 || batch[i + 1] != b) gend[b] = i + 1;
}

__global__ __launch_bounds__(128) void k_pool(const float* __restrict__ X, const int* __restrict__ gstart,
                                              const int* __restrict__ gend, float* __restrict__ pool) {
  int g = blockIdx.x, t = threadIdx.x;
  float s = 0.f;
  int n0 = gstart[g], n1 = gend[g];
  for (int n = n0; n < n1; ++n) s += X[(size_t)n * FT + t];
  pool[g * FT + t] = s;
}

// ---------------- MLP head ----------------

__global__ __launch_bounds__(256) void k_fc1(const float* __restrict__ P, const float* __restrict__ W,
                                             const float* __restrict__ B, float* __restrict__ O) {
  __shared__ float sp[FT];
  int g = blockIdx.x, t = threadIdx.x;
  if (t < FT) sp[t] = P[g * FT + t];
  __syncthreads();
  float a0 = B[t], a1 = B[t + 256];
  for (int k = 0; k < FT; ++k) {
    float x = sp[k];
    a0 += x * W[k * F1 + t];
    a1 += x * W[k * F1 + t + 256];
  }
  O[g * F1 + t] = fmaxf(a0, 0.f);
  O[g * F1 + t + 256] = fmaxf(a1, 0.f);
}

__global__ __launch_bounds__(256) void k_bnstats(const float* __restrict__ h, int cols,
                                                 float* __restrict__ bm, float* __restrict__ br) {
  __shared__ float ss[256], s2[256];
  int c = blockIdx.x, t = threadIdx.x;
  float a = 0.f, b = 0.f;
  for (int r = t; r < NG; r += 256) {
    float v = h[r * cols + c];
    a += v; b += v * v;
  }
  ss[t] = a; s2[t] = b; __syncthreads();
  for (int d = 128; d > 0; d >>= 1) {
    if (t < d) { ss[t] += ss[t + d]; s2[t] += s2[t + d]; }
    __syncthreads();
  }
  if (t == 0) {
    float m = ss[0] / NG;
    float var = s2[0] / NG - m * m;
    bm[c] = m;
    br[c] = rsqrtf(var + BN_EPS);
  }
}

__global__ __launch_bounds__(256) void k_fc2(const float* __restrict__ H1, const float* __restrict__ bm,
                                             const float* __restrict__ br, const float* __restrict__ gam,
                                             const float* __restrict__ bet, const float* __restrict__ W,
                                             const float* __restrict__ B, float* __restrict__ O) {
  __shared__ float sh[F1];
  int g = blockIdx.x, t = threadIdx.x;
  for (int k = t; k < F1; k += 256) {
    float v = H1[g * F1 + k];
    sh[k] = (v - bm[k]) * br[k] * gam[k] + bet[k];
  }
  __syncthreads();
  float a = B[t];
  for (int k = 0; k < F1; ++k) a += sh[k] * W[k * F2 + t];
  O[g * F2 + t] = fmaxf(a, 0.f);
}

__global__ __launch_bounds__(256) void k_fc3(const float* __restrict__ H2, const float* __restrict__ bm,
                                             const float* __restrict__ br, const float* __restrict__ gam,
                                             const float* __restrict__ bet, const float* __restrict__ W,
                                             const float* __restrict__ B, float* __restrict__ O) {
  __shared__ float sh[F2];
  int g = blockIdx.x, t = threadIdx.x;
  if (t < F2) {
    float v = H2[g * F2 + t];
    sh[t] = (v - bm[t]) * br[t] * gam[t] + bet[t];
  }
  __syncthreads();
  if (t < NC) {
    float a = B[t];
    for (int k = 0; k < F2; ++k) a += sh[k] * W[k * NC + t];
    O[g * NC + t] = 1.f / (1.f + expf(-a));
  }
}

// ---------------- launch ----------------

extern "C" void kernel_launch(void* const* d_in, const int* in_sizes, int n_in,
                              void* d_out, int out_size, void* d_ws, size_t ws_size,
                              hipStream_t stream) {
  const float* x     = (const float*)d_in[0];
  const int*   ei    = (const int*)d_in[1];
  const int*   batch = (const int*)d_in[2];
  const float* Wc[4] = {(const float*)d_in[3], (const float*)d_in[5], (const float*)d_in[7], (const float*)d_in[9]};
  const float* Bc[4] = {(const float*)d_in[4], (const float*)d_in[6], (const float*)d_in[8], (const float*)d_in[10]};
  const float* lw1 = (const float*)d_in[11]; const float* lb1 = (const float*)d_in[12];
  const float* lw2 = (const float*)d_in[13]; const float* lb2 = (const float*)d_in[14];
  const float* lw3 = (const float*)d_in[15]; const float* lb3 = (const float*)d_in[16];
  const float* g1  = (const float*)d_in[17]; const float* be1 = (const float*)d_in[18];
  const float* g2  = (const float*)d_in[19]; const float* be2 = (const float*)d_in[20];

  char* p = (char*)d_ws;
  auto take = [&](size_t bytes) {
    char* r = p;
    p += (bytes + 255) & ~(size_t)255;
    return r;
  };
  int*   cnt    = (int*)take((size_t)NN * 4);
  float* dinv   = (float*)take((size_t)NN * 4);
  int*   off    = (int*)take((size_t)(NN + 1) * 4);
  int*   cur    = (int*)take((size_t)NN * 4);
  int*   bsum   = (int*)take(256 * 4);
  int*   bscan  = (int*)take(256 * 4);
  int*   gstart = (int*)take((size_t)NG * 4);
  int*   gend   = (int*)take((size_t)NG * 4);
  int2*  ep     = (int2*)take((size_t)NE * 8);
  float* bufT   = (float*)take((size_t)NN * FT * 4);   // chunk-major GEMM out
  float* bufA   = (float*)take((size_t)NN * FT * 4);
  float* bufB   = (float*)take((size_t)NN * FT * 4);
  float* pool   = (float*)take((size_t)NG * FT * 4);
  float* h1     = (float*)take((size_t)NG * F1 * 4);
  float* h2     = (float*)take((size_t)NG * F2 * 4);
  float* bnm1   = (float*)take(F1 * 4);
  float* bnr1   = (float*)take(F1 * 4);
  float* bnm2   = (float*)take(F2 * 4);
  float* bnr2   = (float*)take(F2 * 4);

  const int NB = (NN + 255) / 256;  // 196

  hipMemsetAsync(cnt, 0, (size_t)NN * 4, stream);
  hipMemsetAsync(cur, 0, (size_t)NN * 4, stream);
  hipMemsetAsync(gstart, 0, (size_t)NG * 4, stream);
  hipMemsetAsync(gend, 0, (size_t)NG * 4, stream);

  k_hist<<<NE / 256, 256, 0, stream>>>(ei, cnt);
  k_dinv<<<NB, 256, 0, stream>>>(cnt, dinv);
  k_scan1<<<NB, 256, 0, stream>>>(cnt, bsum);
  k_scan2<<<1, 256, 0, stream>>>(bsum, bscan, NB);
  k_scan3<<<NB, 256, 0, stream>>>(cnt, bscan, off);
  k_fill<<<NE / 256, 256, 0, stream>>>(ei, off, cur, dinv, ep);

  const int NGRP = (NN + 63) / 64;  // 782
  const float* in = x;
  float* outs[4] = {bufA, bufB, bufA, bufB};
  for (int l = 0; l < 4; ++l) {
    k_gemm<<<NN / 16, 256, 0, stream>>>(in, Wc[l], bufT, NN);
    k_aggc<<<NGRP * 8, 256, 0, stream>>>(bufT, dinv, off, ep, Bc[l], outs[l]);
    in = outs[l];
  }

  k_bounds<<<NB, 256, 0, stream>>>(batch, gstart, gend);
  k_pool<<<NG, 128, 0, stream>>>(bufB, gstart, gend, pool);

  k_fc1<<<NG, 256, 0, stream>>>(pool, lw1, lb1, h1);
  k_bnstats<<<F1, 256, 0, stream>>>(h1, F1, bnm1, bnr1);
  k_fc2<<<NG, 256, 0, stream>>>(h1, bnm1, bnr1, g1, be1, lw2, lb2, h2);
  k_bnstats<<<F2, 256, 0, stream>>>(h2, F2, bnm2, bnr2);
  k_fc3<<<NG, 256, 0, stream>>>(h2, bnm2, bnr2, g2, be2, lw3, lb3, (float*)d_out);
}